// Round 16
// baseline (132.279 us; speedup 1.0000x reference)
//
#include <hip/hip_runtime.h>
#include <math.h>

// ScoreNet: B=8, NV=512, C=256, H=6, R=32, PAIR_H=16, RBF_K=8
// R16: k_pairs occupancy fix (diag showed VGPR=64, grid was the occupancy cap):
//   * body = R12/R13 non-divergent version (VGPR tables; R14's if(hf) reduce
//     was lane-divergent -> both 128-op bodies executed under exec mask)
//   * __launch_bounds__(256,7) (VGPR cap 73) + grid 2048 -> 7-8 waves/SIMD
//     (was 4), stride 8192 waves = exactly 4 iters/wave.
// k_prep/k_uv/k_gemm unchanged. Diagnostic dispatch removed.

#define UK 224

typedef __attribute__((ext_vector_type(8)))  short short8;
typedef __attribute__((ext_vector_type(16))) float f32x16;
typedef __attribute__((ext_vector_type(4)))  int   int4v;

__device__ __forceinline__ float sigmoidf_(float x){ return 1.0f/(1.0f + __expf(-x)); }
__device__ __forceinline__ unsigned f2bf(float x){
    unsigned u = __builtin_bit_cast(unsigned, x);
    return (u + 0x7fffu + ((u>>16)&1u)) >> 16;       // RNE f32->bf16
}
__device__ __forceinline__ unsigned pk2(float lo, float hi){
    unsigned r;
    asm("v_cvt_pk_bf16_f32 %0, %1, %2" : "=v"(r) : "v"(lo), "v"(hi));
    return r;
}
__device__ __forceinline__ f32x16 zero16(){
    f32x16 z;
    #pragma unroll
    for (int i = 0; i < 16; i++) z[i] = 0.f;
    return z;
}

// merged: blocks <4096 pool feats -> bf16 xb; blocks >=4096 pack WT (transposed, bf16) + bcat
__global__ __launch_bounds__(256) void k_prep(const float* __restrict__ feats,
        const float* __restrict__ Wq, const float* __restrict__ Wk,
        const float* __restrict__ Wpi, const float* __restrict__ bpi,
        const float* __restrict__ Wpj, const float* __restrict__ bpj,
        const float* __restrict__ dW, const float* __restrict__ db,
        const float* __restrict__ a_pair,
        unsigned short* __restrict__ xb, unsigned short* __restrict__ WT,
        float* __restrict__ bcat){
    int blk = blockIdx.x, tid = threadIdx.x;
    if (blk < 4096){
        int b = blk >> 9, n = blk & 511;
        size_t base = ((size_t)(b*1025 + 1 + 2*n))*256 + tid;
        float v = 0.5f*(feats[base] + feats[base+256]);
        xb[(size_t)blk*256 + tid] = (unsigned short)f2bf(v);
    } else {
        int col = blk - 4096;    // 0..447
        int c   = tid;           // k index 0..255
        const float invSqrtR = 0.17677669529663687f; // 1/sqrt(32)
        float sp = 1.5f*sigmoidf_(a_pair[0]);
        float v;
        if      (col < 192)  v = Wq[c*192 + col]*invSqrtR;
        else if (col < 208)  v = sp*Wpi[c*16 + (col-192)];
        else if (col < 400)  v = Wk[c*192 + (col-208)];
        else if (col < 416)  v = Wpj[c*16 + (col-400)];
        else if (col == 416) v = dW[c];
        else v = 0.f;
        WT[col*256 + c] = (unsigned short)f2bf(v);
        if (tid == 0){
            float bv = 0.f;
            if      (col >= 192 && col < 208) bv = sp*bpi[col-192];
            else if (col >= 400 && col < 416) bv = bpj[col-400];
            else if (col == 416)              bv = db[0];
            bcat[col] = bv;
        }
    }
}

// xb[4096][256] @ WT^T -> routed to Ub/Vb (bf16, [4096][224], zero-padded) + dv
__global__ __launch_bounds__(256) void k_uv(const unsigned short* __restrict__ xb,
        const unsigned short* __restrict__ WT, const float* __restrict__ bcat,
        unsigned short* __restrict__ Ub, unsigned short* __restrict__ Vb,
        float* __restrict__ dv){
    int tid = threadIdx.x;
    int lane = tid & 63, l31 = lane & 31, hf = lane >> 5;
    int w = tid >> 6, wr = w >> 1, wc = w & 1;
    int c0 = blockIdx.x*64, r0 = blockIdx.y*64;
    const unsigned short* ap = xb + (size_t)(r0 + wr*32 + l31)*256 + 8*hf;
    const unsigned short* bp = WT + (size_t)(c0 + wc*32 + l31)*256 + 8*hf;
    f32x16 acc = zero16();
    #pragma unroll 4
    for (int k0 = 0; k0 < 256; k0 += 16){
        short8 a  = *(const short8*)(ap + k0);
        short8 bb = *(const short8*)(bp + k0);
        acc = __builtin_amdgcn_mfma_f32_32x32x16_bf16(a, bb, acc, 0, 0, 0);
    }
    int col = c0 + wc*32 + l31;          // uniform per lane across all 16 accs
    int rb  = r0 + wr*32 + 4*hf;
    float bc = bcat[col];
    #pragma unroll
    for (int r = 0; r < 16; r++){
        int row = rb + (r&3) + 8*(r>>2);
        float v = acc[r] + bc;
        size_t ui = (size_t)row*UK;
        if (col < 208){
            if (col >= 192) v = fmaxf(v, 0.f);        // a_i relu
            Ub[ui + col] = (unsigned short)f2bf(v);
        } else if (col < 224){
            Vb[ui + col-208] = (unsigned short)f2bf(v);
            Ub[ui + col] = 0;                          // Ub K-pad
        } else if (col < 416){
            if (col >= 400) v = fmaxf(v, 0.f);        // b_j relu
            Vb[ui + col-208] = (unsigned short)f2bf(v);
        } else if (col == 416){
            dv[row] = v;
            Vb[ui + 208] = 0;                          // Vb K-pad
        } else if (col < 432){
            Vb[ui + col-208] = 0;                      // Vb K-pad (cols 417..431 are zero-cols)
        }
        // col >= 432: dead padding, skip
    }
}

// S_lin[b][n][m] = Ub[b,n,:] . Vb[b,m,:]  (bf16 MFMA, K=224 incl. zero pad)
__global__ __launch_bounds__(256) void k_gemm(const unsigned short* __restrict__ Ub,
        const unsigned short* __restrict__ Vb, float* __restrict__ S){
    int tid = threadIdx.x;
    int lane = tid & 63, l31 = lane & 31, hf = lane >> 5;
    int w = tid >> 6, wr = w >> 1, wc = w & 1;
    int b = blockIdx.z;
    int m0 = blockIdx.x*64, n0 = blockIdx.y*64;
    const unsigned short* ap = Ub + (size_t)(b*512 + n0 + wr*32 + l31)*UK + 8*hf;
    const unsigned short* bp = Vb + (size_t)(b*512 + m0 + wc*32 + l31)*UK + 8*hf;
    f32x16 acc = zero16();
    #pragma unroll 2
    for (int k0 = 0; k0 < UK; k0 += 16){
        short8 a  = *(const short8*)(ap + k0);
        short8 bb = *(const short8*)(bp + k0);
        acc = __builtin_amdgcn_mfma_f32_32x32x16_bf16(a, bb, acc, 0, 0, 0);
    }
    int m  = m0 + wc*32 + l31;
    int nb = n0 + wr*32 + 4*hf;
    float* Sp = S + ((size_t)b*512)*512 + m;
    #pragma unroll
    for (int r = 0; r < 16; r++){
        int n = nb + (r&3) + 8*(r>>2);
        Sp[(size_t)n*512] = acc[r];
    }
}

// per-pair geom + angle MLPs via MFMA; in-place RMW on S
// R12/R13 non-divergent body; grid 2048, __launch_bounds__(256,7) -> 7+ waves/SIMD
__global__ __launch_bounds__(256, 7) void k_pairs(const float* __restrict__ xy,
        const float* __restrict__ gW1, const float* __restrict__ gb1,
        const float* __restrict__ gW2, const float* __restrict__ gb2,
        const float* __restrict__ aW1, const float* __restrict__ ab1,
        const float* __restrict__ aW2, const float* __restrict__ ab2,
        const float* __restrict__ dv,
        const float* __restrict__ a_geom, const float* __restrict__ a_ang,
        const float* __restrict__ lsc,
        float* __restrict__ S){
    int tid  = threadIdx.x;
    int lane = tid & 63;
    int hf   = lane >> 5;
    int l31  = lane & 31;

    float sg = 1.5f*sigmoidf_(a_geom[0]);
    float sa = 1.5f*sigmoidf_(a_ang[0]);
    float ls = 0.5f + 2.5f*sigmoidf_(lsc[0]);

    short8 wg, wa;
    #pragma unroll
    for (int j = 0; j < 8; j++){
        int f = hf*8 + j;
        float vg = (f < 12) ? gW1[f*32 + l31] : 0.f;
        float va = (f >= 10 && l31 < 16) ? aW1[(f-10)*16 + l31] : 0.f;
        wg[j] = (short)f2bf(vg);
        wa[j] = (short)f2bf(va);
    }

    float nbg[16], g2g[16], nba[16], g2a[16];
    float bsum = 0.f;
    #pragma unroll
    for (int r = 0; r < 16; r++){
        int h = (r&3) + 8*(r>>2) + 4*hf;
        float bg  = gb1[h];
        float wg2 = sg*gW2[h];
        nbg[r] = -bg; g2g[r] = wg2; bsum += bg*wg2;
        if (h < 16){
            float ba  = ab1[h];
            float wa2 = sa*aW2[h];
            nba[r] = -ba; g2a[r] = wa2; bsum += ba*wa2;
        } else { nba[r] = 0.f; g2a[r] = 0.f; }
    }
    bsum += __shfl_xor(bsum, 32);
    float cb = sg*gb2[0] + sa*ab2[0] + bsum;

    const float GAMMA = 12.2499985f;    // 1/(2*spacing^2 + 1e-8)
    const float TWOGD = 4.9497469f;     // 2*GAMMA*spacing

    int wid = __builtin_amdgcn_readfirstlane(tid >> 6);
    int wave_g = blockIdx.x*4 + wid;            // 2048*4 = 8192 waves, 4 iters each
    for (int c = wave_g; c < 32768; c += 8192){
        int base = c*64;
        int nn = (base >> 9) & 511;             // wave-uniform
        int bb = base >> 18;                    // wave-uniform
        const float* xyb = xy + (size_t)bb*1024;
        float yn = xyb[2*nn], xn = xyb[2*nn+1];
        bool padn = (fabsf(yn) < 1e-9f) && (fabsf(xn) < 1e-9f);
        float sv  = S[(size_t)base + lane];     // prefetch RMW value (coalesced)
        float dvn = dv[bb*512 + nn];

        unsigned fA0, fA1, fA2, fA3, fB0, fB1, fB2, fB3;
        float mA, mB;
        #pragma unroll
        for (int ch = 0; ch < 2; ch++){
            int pidx = base + ch*32 + l31;
            float2 pm = *(const float2*)(xyb + 2*(pidx & 511));
            float ym = pm.x, xm = pm.y;
            bool padm = (fabsf(ym) < 1e-9f) && (fabsf(xm) < 1e-9f);
            float msk = (padn || padm) ? 0.f : 1.f;
            float dy = yn - ym, dx = xn - xm;
            float r2 = dy*dy + dx*dx;
            float re = sqrtf(r2 + 1e-8f);
            float c1, s1;
            if (r2 > 0.f){ float inv = rsqrtf(r2); c1 = dx*inv; s1 = dy*inv; }
            else { c1 = 1.f; s1 = 0.f; }        // atan2(0,0)=0
            float c2 = c1*c1 - s1*s1, s2 = 2.f*c1*s1;
            float c4 = c2*c2 - s2*s2, s4 = 2.f*c2*s2;
            float e0 = __expf(-GAMMA*(r2 + 1e-8f));
            float E  = __expf(TWOGD*re);
            float u  = e0;
            float p0 = u;
            u *= E; float p1 = 0.60653066f*u;
            u *= E; float p2 = 0.13533528f*u;
            u *= E; float p3 = 0.011108997f*u;
            u *= E; float p4 = 3.3546263e-4f*u;
            u *= E; float p5 = 3.7266532e-6f*u;
            u *= E; float p6 = 1.5229979e-8f*u;
            u *= E; float p7 = 2.2897348e-11f*u;
            unsigned w0 = hf ? pk2(p6, p7) : pk2(dy, dx);
            unsigned w1 = hf ? pk2(c1, s1) : pk2(p0, p1);
            unsigned w2 = hf ? pk2(c2, s2) : pk2(p2, p3);
            unsigned w3 = hf ? pk2(c4, s4) : pk2(p4, p5);
            if (ch == 0){ fA0=w0; fA1=w1; fA2=w2; fA3=w3; mA = msk; }
            else        { fB0=w0; fB1=w1; fB2=w2; fB3=w3; mB = msk; }
        }
        int4v ivA = {(int)fA0, (int)fA1, (int)fA2, (int)fA3};
        int4v ivB = {(int)fB0, (int)fB1, (int)fB2, (int)fB3};
        short8 bfA = __builtin_bit_cast(short8, ivA);
        short8 bfB = __builtin_bit_cast(short8, ivB);

        f32x16 z = zero16();
        f32x16 dgA = __builtin_amdgcn_mfma_f32_32x32x16_bf16(wg, bfA, z, 0, 0, 0);
        f32x16 dgB = __builtin_amdgcn_mfma_f32_32x32x16_bf16(wg, bfB, z, 0, 0, 0);
        f32x16 daA = __builtin_amdgcn_mfma_f32_32x32x16_bf16(wa, bfA, z, 0, 0, 0);
        f32x16 daB = __builtin_amdgcn_mfma_f32_32x32x16_bf16(wa, bfB, z, 0, 0, 0);

        float accA = 0.f, accB = 0.f;
        #pragma unroll
        for (int r = 0; r < 16; r++){
            accA += fmaxf(dgA[r], nbg[r]) * g2g[r];
            accB += fmaxf(dgB[r], nbg[r]) * g2g[r];
        }
        #pragma unroll
        for (int r = 0; r < 16; r++){
            accA += fmaxf(daA[r], nba[r]) * g2a[r];
            accB += fmaxf(daB[r], nba[r]) * g2a[r];
        }
        accA += __shfl_xor(accA, 32);
        accB += __shfl_xor(accB, 32);

        float res  = (lane < 32) ? accA : accB;   // write pair = base+lane
        float mskw = (lane < 32) ? mA : mB;
        int m_w = (base + lane) & 511;
        float ddg = (m_w == nn) ? dvn : 0.f;
        S[(size_t)base + lane] = (sv + mskw*(res + cb) + ddg) * ls;
    }
}

extern "C" void kernel_launch(void* const* d_in, const int* in_sizes, int n_in,
                              void* d_out, int out_size, void* d_ws, size_t ws_size,
                              hipStream_t stream){
    const float* feats = (const float*)d_in[0];
    const float* xy    = (const float*)d_in[1];
    const float* Wq    = (const float*)d_in[2];
    const float* Wk    = (const float*)d_in[3];
    const float* Wpi   = (const float*)d_in[4];
    const float* bpi   = (const float*)d_in[5];
    const float* Wpj   = (const float*)d_in[6];
    const float* bpj   = (const float*)d_in[7];
    const float* gW1   = (const float*)d_in[8];
    const float* gb1   = (const float*)d_in[9];
    const float* gW2   = (const float*)d_in[10];
    const float* gb2   = (const float*)d_in[11];
    const float* aW1   = (const float*)d_in[12];
    const float* ab1   = (const float*)d_in[13];
    const float* aW2   = (const float*)d_in[14];
    const float* ab2   = (const float*)d_in[15];
    const float* dW    = (const float*)d_in[16];
    const float* db    = (const float*)d_in[17];
    const float* a_pair= (const float*)d_in[18];
    const float* a_geom= (const float*)d_in[19];
    const float* a_ang = (const float*)d_in[20];
    const float* lsc   = (const float*)d_in[21];

    float* S = (float*)d_out;
    char* wsb = (char*)d_ws;
    unsigned short* xb = (unsigned short*)wsb;                    // 4096*256*2 = 2,097,152 B
    unsigned short* WT = (unsigned short*)(wsb + 2097152);        // 448*256*2  =   229,376 B
    unsigned short* Ub = (unsigned short*)(wsb + 2326528);        // 4096*224*2 = 1,835,008 B
    unsigned short* Vb = (unsigned short*)(wsb + 4161536);        // 1,835,008 B
    float* bcat = (float*)(wsb + 5996544);                        // 448*4
    float* dv   = (float*)(wsb + 5998336);                        // 4096*4
    // total ~6.0 MB of d_ws

    k_prep <<<4544, 256, 0, stream>>>(feats, Wq, Wk, Wpi, bpi, Wpj, bpj, dW, db, a_pair,
                                      xb, WT, bcat);
    k_uv   <<<dim3(7,64), 256, 0, stream>>>(xb, WT, bcat, Ub, Vb, dv);
    k_gemm <<<dim3(8,8,8), 256, 0, stream>>>(Ub, Vb, S);
    k_pairs<<<2048, 256, 0, stream>>>(xy, gW1, gb1, gW2, gb2, aW1, ab1, aW2, ab2,
                                      dv, a_geom, a_ang, lsc, S);
}

// Round 17
// 53.801 us; speedup vs baseline: 2.4587x; 2.4587x over previous
//
#include <hip/hip_runtime.h>
#include <math.h>

// ScoreNet: B=8, NV=512, C=256, H=6, R=32, PAIR_H=16, RBF_K=8
// R17 (k_pairs): R16's (256,7) spilled to scratch (VGPR 36 + 221MB FETCH —
//   true footprint ~128 incl. 64 unified-file AGPR accumulators). Fixes:
//   1. launch_bounds back to (256,3) (known-good, no spill)
//   2. tree-reduce: 8 independent partial chains of 8 (was 2x64 serial
//      dependent FMAs ~512cyc unhideable latency/iter)
//   3. feature dedup (R14's verified shfl_xor exchange) + NON-divergent
//      VGPR-table reduce (R14's divergent if(hf) reduce ate the dedup gain)
// k_prep/k_uv/k_gemm unchanged.

#define UK 224

typedef __attribute__((ext_vector_type(8)))  short short8;
typedef __attribute__((ext_vector_type(16))) float f32x16;
typedef __attribute__((ext_vector_type(4)))  int   int4v;

__device__ __forceinline__ float sigmoidf_(float x){ return 1.0f/(1.0f + __expf(-x)); }
__device__ __forceinline__ unsigned f2bf(float x){
    unsigned u = __builtin_bit_cast(unsigned, x);
    return (u + 0x7fffu + ((u>>16)&1u)) >> 16;       // RNE f32->bf16
}
__device__ __forceinline__ unsigned pk2(float lo, float hi){
    unsigned r;
    asm("v_cvt_pk_bf16_f32 %0, %1, %2" : "=v"(r) : "v"(lo), "v"(hi));
    return r;
}
__device__ __forceinline__ f32x16 zero16(){
    f32x16 z;
    #pragma unroll
    for (int i = 0; i < 16; i++) z[i] = 0.f;
    return z;
}

// merged: blocks <4096 pool feats -> bf16 xb; blocks >=4096 pack WT (transposed, bf16) + bcat
__global__ __launch_bounds__(256) void k_prep(const float* __restrict__ feats,
        const float* __restrict__ Wq, const float* __restrict__ Wk,
        const float* __restrict__ Wpi, const float* __restrict__ bpi,
        const float* __restrict__ Wpj, const float* __restrict__ bpj,
        const float* __restrict__ dW, const float* __restrict__ db,
        const float* __restrict__ a_pair,
        unsigned short* __restrict__ xb, unsigned short* __restrict__ WT,
        float* __restrict__ bcat){
    int blk = blockIdx.x, tid = threadIdx.x;
    if (blk < 4096){
        int b = blk >> 9, n = blk & 511;
        size_t base = ((size_t)(b*1025 + 1 + 2*n))*256 + tid;
        float v = 0.5f*(feats[base] + feats[base+256]);
        xb[(size_t)blk*256 + tid] = (unsigned short)f2bf(v);
    } else {
        int col = blk - 4096;    // 0..447
        int c   = tid;           // k index 0..255
        const float invSqrtR = 0.17677669529663687f; // 1/sqrt(32)
        float sp = 1.5f*sigmoidf_(a_pair[0]);
        float v;
        if      (col < 192)  v = Wq[c*192 + col]*invSqrtR;
        else if (col < 208)  v = sp*Wpi[c*16 + (col-192)];
        else if (col < 400)  v = Wk[c*192 + (col-208)];
        else if (col < 416)  v = Wpj[c*16 + (col-400)];
        else if (col == 416) v = dW[c];
        else v = 0.f;
        WT[col*256 + c] = (unsigned short)f2bf(v);
        if (tid == 0){
            float bv = 0.f;
            if      (col >= 192 && col < 208) bv = sp*bpi[col-192];
            else if (col >= 400 && col < 416) bv = bpj[col-400];
            else if (col == 416)              bv = db[0];
            bcat[col] = bv;
        }
    }
}

// xb[4096][256] @ WT^T -> routed to Ub/Vb (bf16, [4096][224], zero-padded) + dv
__global__ __launch_bounds__(256) void k_uv(const unsigned short* __restrict__ xb,
        const unsigned short* __restrict__ WT, const float* __restrict__ bcat,
        unsigned short* __restrict__ Ub, unsigned short* __restrict__ Vb,
        float* __restrict__ dv){
    int tid = threadIdx.x;
    int lane = tid & 63, l31 = lane & 31, hf = lane >> 5;
    int w = tid >> 6, wr = w >> 1, wc = w & 1;
    int c0 = blockIdx.x*64, r0 = blockIdx.y*64;
    const unsigned short* ap = xb + (size_t)(r0 + wr*32 + l31)*256 + 8*hf;
    const unsigned short* bp = WT + (size_t)(c0 + wc*32 + l31)*256 + 8*hf;
    f32x16 acc = zero16();
    #pragma unroll 4
    for (int k0 = 0; k0 < 256; k0 += 16){
        short8 a  = *(const short8*)(ap + k0);
        short8 bb = *(const short8*)(bp + k0);
        acc = __builtin_amdgcn_mfma_f32_32x32x16_bf16(a, bb, acc, 0, 0, 0);
    }
    int col = c0 + wc*32 + l31;          // uniform per lane across all 16 accs
    int rb  = r0 + wr*32 + 4*hf;
    float bc = bcat[col];
    #pragma unroll
    for (int r = 0; r < 16; r++){
        int row = rb + (r&3) + 8*(r>>2);
        float v = acc[r] + bc;
        size_t ui = (size_t)row*UK;
        if (col < 208){
            if (col >= 192) v = fmaxf(v, 0.f);        // a_i relu
            Ub[ui + col] = (unsigned short)f2bf(v);
        } else if (col < 224){
            Vb[ui + col-208] = (unsigned short)f2bf(v);
            Ub[ui + col] = 0;                          // Ub K-pad
        } else if (col < 416){
            if (col >= 400) v = fmaxf(v, 0.f);        // b_j relu
            Vb[ui + col-208] = (unsigned short)f2bf(v);
        } else if (col == 416){
            dv[row] = v;
            Vb[ui + 208] = 0;                          // Vb K-pad
        } else if (col < 432){
            Vb[ui + col-208] = 0;                      // Vb K-pad (cols 417..431 are zero-cols)
        }
        // col >= 432: dead padding, skip
    }
}

// S_lin[b][n][m] = Ub[b,n,:] . Vb[b,m,:]  (bf16 MFMA, K=224 incl. zero pad)
__global__ __launch_bounds__(256) void k_gemm(const unsigned short* __restrict__ Ub,
        const unsigned short* __restrict__ Vb, float* __restrict__ S){
    int tid = threadIdx.x;
    int lane = tid & 63, l31 = lane & 31, hf = lane >> 5;
    int w = tid >> 6, wr = w >> 1, wc = w & 1;
    int b = blockIdx.z;
    int m0 = blockIdx.x*64, n0 = blockIdx.y*64;
    const unsigned short* ap = Ub + (size_t)(b*512 + n0 + wr*32 + l31)*UK + 8*hf;
    const unsigned short* bp = Vb + (size_t)(b*512 + m0 + wc*32 + l31)*UK + 8*hf;
    f32x16 acc = zero16();
    #pragma unroll 2
    for (int k0 = 0; k0 < UK; k0 += 16){
        short8 a  = *(const short8*)(ap + k0);
        short8 bb = *(const short8*)(bp + k0);
        acc = __builtin_amdgcn_mfma_f32_32x32x16_bf16(a, bb, acc, 0, 0, 0);
    }
    int m  = m0 + wc*32 + l31;
    int nb = n0 + wr*32 + 4*hf;
    float* Sp = S + ((size_t)b*512)*512 + m;
    #pragma unroll
    for (int r = 0; r < 16; r++){
        int n = nb + (r&3) + 8*(r>>2);
        Sp[(size_t)n*512] = acc[r];
    }
}

// per-pair geom + angle MLPs via MFMA; in-place RMW on S
// Lane computes OWN pair (base+lane) features once; 4 shfl_xor exchange the
// partner k-halves (selection inside shfl evaluated in SOURCE lane: hf=0
// sends pk4..7, hf=1 sends pk0..3 -> receiver gets what it needs).
// Reduce: non-divergent VGPR tables, 8 independent partial chains of 8.
__global__ __launch_bounds__(256, 3) void k_pairs(const float* __restrict__ xy,
        const float* __restrict__ gW1, const float* __restrict__ gb1,
        const float* __restrict__ gW2, const float* __restrict__ gb2,
        const float* __restrict__ aW1, const float* __restrict__ ab1,
        const float* __restrict__ aW2, const float* __restrict__ ab2,
        const float* __restrict__ dv,
        const float* __restrict__ a_geom, const float* __restrict__ a_ang,
        const float* __restrict__ lsc,
        float* __restrict__ S){
    int tid  = threadIdx.x;
    int lane = tid & 63;
    int hf   = lane >> 5;
    int l31  = lane & 31;

    float sg = 1.5f*sigmoidf_(a_geom[0]);
    float sa = 1.5f*sigmoidf_(a_ang[0]);
    float ls = 0.5f + 2.5f*sigmoidf_(lsc[0]);

    short8 wg, wa;
    #pragma unroll
    for (int j = 0; j < 8; j++){
        int f = hf*8 + j;
        float vg = (f < 12) ? gW1[f*32 + l31] : 0.f;
        float va = (f >= 10 && l31 < 16) ? aW1[(f-10)*16 + l31] : 0.f;
        wg[j] = (short)f2bf(vg);
        wa[j] = (short)f2bf(va);
    }

    float nbg[16], g2g[16], nba[16], g2a[16];
    float bsum = 0.f;
    #pragma unroll
    for (int r = 0; r < 16; r++){
        int h = (r&3) + 8*(r>>2) + 4*hf;
        float bg  = gb1[h];
        float wg2 = sg*gW2[h];
        nbg[r] = -bg; g2g[r] = wg2; bsum += bg*wg2;
        if (h < 16){
            float ba  = ab1[h];
            float wa2 = sa*aW2[h];
            nba[r] = -ba; g2a[r] = wa2; bsum += ba*wa2;
        } else { nba[r] = 0.f; g2a[r] = 0.f; }
    }
    bsum += __shfl_xor(bsum, 32);
    float cb = sg*gb2[0] + sa*ab2[0] + bsum;

    const float GAMMA = 12.2499985f;    // 1/(2*spacing^2 + 1e-8)
    const float TWOGD = 4.9497469f;     // 2*GAMMA*spacing

    int wid = __builtin_amdgcn_readfirstlane(tid >> 6);
    int wave_g = blockIdx.x*4 + wid;            // 2048*4 = 8192 waves, 4 iters
    for (int c = wave_g; c < 32768; c += 8192){
        int base = c*64;
        int nn = (base >> 9) & 511;             // wave-uniform
        int bb = base >> 18;                    // wave-uniform
        const float* xyb = xy + (size_t)bb*1024;
        float yn = xyb[2*nn], xn = xyb[2*nn+1];
        bool padn = (fabsf(yn) < 1e-9f) && (fabsf(xn) < 1e-9f);
        float sv  = S[(size_t)base + lane];     // prefetch RMW value (coalesced)
        float dvn = dv[bb*512 + nn];
        int m_w = (base + lane) & 511;
        float ddg = (m_w == nn) ? dvn : 0.f;

        // OWN pair features (computed once per pair, per lane)
        float2 pm = *(const float2*)(xyb + 2*m_w);
        float ym = pm.x, xm = pm.y;
        bool padm = (fabsf(ym) < 1e-9f) && (fabsf(xm) < 1e-9f);
        float msk = (padn || padm) ? 0.f : 1.f;
        float dy = yn - ym, dx = xn - xm;
        float r2 = dy*dy + dx*dx;
        float re = sqrtf(r2 + 1e-8f);
        float c1, s1;
        if (r2 > 0.f){ float inv = rsqrtf(r2); c1 = dx*inv; s1 = dy*inv; }
        else { c1 = 1.f; s1 = 0.f; }            // atan2(0,0)=0
        float c2 = c1*c1 - s1*s1, s2 = 2.f*c1*s1;
        float c4 = c2*c2 - s2*s2, s4 = 2.f*c2*s2;
        float e0 = __expf(-GAMMA*(r2 + 1e-8f));
        float E  = __expf(TWOGD*re);
        float u  = e0;
        float p0 = u;
        u *= E; float p1 = 0.60653066f*u;
        u *= E; float p2 = 0.13533528f*u;
        u *= E; float p3 = 0.011108997f*u;
        u *= E; float p4 = 3.3546263e-4f*u;
        u *= E; float p5 = 3.7266532e-6f*u;
        u *= E; float p6 = 1.5229979e-8f*u;
        u *= E; float p7 = 2.2897348e-11f*u;
        unsigned pk0 = pk2(dy, dx), pk1 = pk2(p0, p1), pk2_ = pk2(p2, p3), pk3 = pk2(p4, p5);
        unsigned pk4 = pk2(p6, p7), pk5 = pk2(c1, s1), pk6 = pk2(c2, s2), pk7 = pk2(c4, s4);

        // exchange partner halves (selection evaluated in SOURCE lane)
        int s0 = __shfl_xor((int)(hf ? pk0 : pk4), 32);
        int s1i= __shfl_xor((int)(hf ? pk1 : pk5), 32);
        int s2i= __shfl_xor((int)(hf ? pk2_: pk6), 32);
        int s3i= __shfl_xor((int)(hf ? pk3 : pk7), 32);

        int fA0 = hf ? s0 : (int)pk0, fA1 = hf ? s1i : (int)pk1;
        int fA2 = hf ? s2i : (int)pk2_, fA3 = hf ? s3i : (int)pk3;
        int fB0 = hf ? (int)pk4 : s0,  fB1 = hf ? (int)pk5 : s1i;
        int fB2 = hf ? (int)pk6 : s2i, fB3 = hf ? (int)pk7 : s3i;
        int4v ivA = {fA0, fA1, fA2, fA3};
        int4v ivB = {fB0, fB1, fB2, fB3};
        short8 bfA = __builtin_bit_cast(short8, ivA);
        short8 bfB = __builtin_bit_cast(short8, ivB);

        f32x16 z = zero16();
        f32x16 dgA = __builtin_amdgcn_mfma_f32_32x32x16_bf16(wg, bfA, z, 0, 0, 0);
        f32x16 dgB = __builtin_amdgcn_mfma_f32_32x32x16_bf16(wg, bfB, z, 0, 0, 0);
        f32x16 daA = __builtin_amdgcn_mfma_f32_32x32x16_bf16(wa, bfA, z, 0, 0, 0);
        f32x16 daB = __builtin_amdgcn_mfma_f32_32x32x16_bf16(wa, bfB, z, 0, 0, 0);

        // tree reduce: 8 independent chains of 8
        float a0=0.f,a1=0.f,a2=0.f,a3=0.f,b0=0.f,b1=0.f,b2=0.f,b3=0.f;
        #pragma unroll
        for (int r = 0; r < 8; r++){
            a0 += fmaxf(dgA[r],   nbg[r])   * g2g[r];
            a1 += fmaxf(dgA[r+8], nbg[r+8]) * g2g[r+8];
            b0 += fmaxf(dgB[r],   nbg[r])   * g2g[r];
            b1 += fmaxf(dgB[r+8], nbg[r+8]) * g2g[r+8];
            a2 += fmaxf(daA[r],   nba[r])   * g2a[r];
            a3 += fmaxf(daA[r+8], nba[r+8]) * g2a[r+8];
            b2 += fmaxf(daB[r],   nba[r])   * g2a[r];
            b3 += fmaxf(daB[r+8], nba[r+8]) * g2a[r+8];
        }
        float accA = (a0 + a1) + (a2 + a3);
        float accB = (b0 + b1) + (b2 + b3);
        accA += __shfl_xor(accA, 32);
        accB += __shfl_xor(accB, 32);

        float res = (lane < 32) ? accA : accB;   // write pair = base+lane
        S[(size_t)base + lane] = (sv + msk*(res + cb) + ddg) * ls;
    }
}

extern "C" void kernel_launch(void* const* d_in, const int* in_sizes, int n_in,
                              void* d_out, int out_size, void* d_ws, size_t ws_size,
                              hipStream_t stream){
    const float* feats = (const float*)d_in[0];
    const float* xy    = (const float*)d_in[1];
    const float* Wq    = (const float*)d_in[2];
    const float* Wk    = (const float*)d_in[3];
    const float* Wpi   = (const float*)d_in[4];
    const float* bpi   = (const float*)d_in[5];
    const float* Wpj   = (const float*)d_in[6];
    const float* bpj   = (const float*)d_in[7];
    const float* gW1   = (const float*)d_in[8];
    const float* gb1   = (const float*)d_in[9];
    const float* gW2   = (const float*)d_in[10];
    const float* gb2   = (const float*)d_in[11];
    const float* aW1   = (const float*)d_in[12];
    const float* ab1   = (const float*)d_in[13];
    const float* aW2   = (const float*)d_in[14];
    const float* ab2   = (const float*)d_in[15];
    const float* dW    = (const float*)d_in[16];
    const float* db    = (const float*)d_in[17];
    const float* a_pair= (const float*)d_in[18];
    const float* a_geom= (const float*)d_in[19];
    const float* a_ang = (const float*)d_in[20];
    const float* lsc   = (const float*)d_in[21];

    float* S = (float*)d_out;
    char* wsb = (char*)d_ws;
    unsigned short* xb = (unsigned short*)wsb;                    // 4096*256*2 = 2,097,152 B
    unsigned short* WT = (unsigned short*)(wsb + 2097152);        // 448*256*2  =   229,376 B
    unsigned short* Ub = (unsigned short*)(wsb + 2326528);        // 4096*224*2 = 1,835,008 B
    unsigned short* Vb = (unsigned short*)(wsb + 4161536);        // 1,835,008 B
    float* bcat = (float*)(wsb + 5996544);                        // 448*4
    float* dv   = (float*)(wsb + 5998336);                        // 4096*4
    // total ~6.0 MB of d_ws

    k_prep <<<4544, 256, 0, stream>>>(feats, Wq, Wk, Wpi, bpi, Wpj, bpj, dW, db, a_pair,
                                      xb, WT, bcat);
    k_uv   <<<dim3(7,64), 256, 0, stream>>>(xb, WT, bcat, Ub, Vb, dv);
    k_gemm <<<dim3(8,8,8), 256, 0, stream>>>(Ub, Vb, S);
    k_pairs<<<2048, 256, 0, stream>>>(xy, gW1, gb1, gW2, gb2, aW1, ab1, aW2, ab2,
                                      dv, a_geom, a_ang, lsc, S);
}

// Round 18
// 52.074 us; speedup vs baseline: 2.5402x; 1.0332x over previous
//
#include <hip/hip_runtime.h>
#include <math.h>

// ScoreNet: B=8, NV=512, C=256, H=6, R=32, PAIR_H=16, RBF_K=8
// R18: fuse k_gemm + k_pairs -> k_gp (eliminates 16MB S round-trip, one
//   launch, cross-XCD S-load stall, and 4x table-setup overhead):
//   phase1 = gemm, acc -> acc_lds[64][64] (frees ACC regs before phase2)
//   phase2 = R17 pair body per tile row; adds msk*(res+cb) into acc_lds
//   phase3 = +diag, *ls, single coalesced S store
// k_prep/k_uv unchanged.

#define UK 224

typedef __attribute__((ext_vector_type(8)))  short short8;
typedef __attribute__((ext_vector_type(16))) float f32x16;
typedef __attribute__((ext_vector_type(4)))  int   int4v;

__device__ __forceinline__ float sigmoidf_(float x){ return 1.0f/(1.0f + __expf(-x)); }
__device__ __forceinline__ unsigned f2bf(float x){
    unsigned u = __builtin_bit_cast(unsigned, x);
    return (u + 0x7fffu + ((u>>16)&1u)) >> 16;       // RNE f32->bf16
}
__device__ __forceinline__ unsigned pk2(float lo, float hi){
    unsigned r;
    asm("v_cvt_pk_bf16_f32 %0, %1, %2" : "=v"(r) : "v"(lo), "v"(hi));
    return r;
}
__device__ __forceinline__ f32x16 zero16(){
    f32x16 z;
    #pragma unroll
    for (int i = 0; i < 16; i++) z[i] = 0.f;
    return z;
}

// merged: blocks <4096 pool feats -> bf16 xb; blocks >=4096 pack WT (transposed, bf16) + bcat
__global__ __launch_bounds__(256) void k_prep(const float* __restrict__ feats,
        const float* __restrict__ Wq, const float* __restrict__ Wk,
        const float* __restrict__ Wpi, const float* __restrict__ bpi,
        const float* __restrict__ Wpj, const float* __restrict__ bpj,
        const float* __restrict__ dW, const float* __restrict__ db,
        const float* __restrict__ a_pair,
        unsigned short* __restrict__ xb, unsigned short* __restrict__ WT,
        float* __restrict__ bcat){
    int blk = blockIdx.x, tid = threadIdx.x;
    if (blk < 4096){
        int b = blk >> 9, n = blk & 511;
        size_t base = ((size_t)(b*1025 + 1 + 2*n))*256 + tid;
        float v = 0.5f*(feats[base] + feats[base+256]);
        xb[(size_t)blk*256 + tid] = (unsigned short)f2bf(v);
    } else {
        int col = blk - 4096;    // 0..447
        int c   = tid;           // k index 0..255
        const float invSqrtR = 0.17677669529663687f; // 1/sqrt(32)
        float sp = 1.5f*sigmoidf_(a_pair[0]);
        float v;
        if      (col < 192)  v = Wq[c*192 + col]*invSqrtR;
        else if (col < 208)  v = sp*Wpi[c*16 + (col-192)];
        else if (col < 400)  v = Wk[c*192 + (col-208)];
        else if (col < 416)  v = Wpj[c*16 + (col-400)];
        else if (col == 416) v = dW[c];
        else v = 0.f;
        WT[col*256 + c] = (unsigned short)f2bf(v);
        if (tid == 0){
            float bv = 0.f;
            if      (col >= 192 && col < 208) bv = sp*bpi[col-192];
            else if (col >= 400 && col < 416) bv = bpj[col-400];
            else if (col == 416)              bv = db[0];
            bcat[col] = bv;
        }
    }
}

// xb[4096][256] @ WT^T -> routed to Ub/Vb (bf16, [4096][224], zero-padded) + dv
__global__ __launch_bounds__(256) void k_uv(const unsigned short* __restrict__ xb,
        const unsigned short* __restrict__ WT, const float* __restrict__ bcat,
        unsigned short* __restrict__ Ub, unsigned short* __restrict__ Vb,
        float* __restrict__ dv){
    int tid = threadIdx.x;
    int lane = tid & 63, l31 = lane & 31, hf = lane >> 5;
    int w = tid >> 6, wr = w >> 1, wc = w & 1;
    int c0 = blockIdx.x*64, r0 = blockIdx.y*64;
    const unsigned short* ap = xb + (size_t)(r0 + wr*32 + l31)*256 + 8*hf;
    const unsigned short* bp = WT + (size_t)(c0 + wc*32 + l31)*256 + 8*hf;
    f32x16 acc = zero16();
    #pragma unroll 4
    for (int k0 = 0; k0 < 256; k0 += 16){
        short8 a  = *(const short8*)(ap + k0);
        short8 bb = *(const short8*)(bp + k0);
        acc = __builtin_amdgcn_mfma_f32_32x32x16_bf16(a, bb, acc, 0, 0, 0);
    }
    int col = c0 + wc*32 + l31;          // uniform per lane across all 16 accs
    int rb  = r0 + wr*32 + 4*hf;
    float bc = bcat[col];
    #pragma unroll
    for (int r = 0; r < 16; r++){
        int row = rb + (r&3) + 8*(r>>2);
        float v = acc[r] + bc;
        size_t ui = (size_t)row*UK;
        if (col < 208){
            if (col >= 192) v = fmaxf(v, 0.f);        // a_i relu
            Ub[ui + col] = (unsigned short)f2bf(v);
        } else if (col < 224){
            Vb[ui + col-208] = (unsigned short)f2bf(v);
            Ub[ui + col] = 0;                          // Ub K-pad
        } else if (col < 416){
            if (col >= 400) v = fmaxf(v, 0.f);        // b_j relu
            Vb[ui + col-208] = (unsigned short)f2bf(v);
        } else if (col == 416){
            dv[row] = v;
            Vb[ui + 208] = 0;                          // Vb K-pad
        } else if (col < 432){
            Vb[ui + col-208] = 0;                      // Vb K-pad (cols 417..431 are zero-cols)
        }
        // col >= 432: dead padding, skip
    }
}

// FUSED: S_lin (bf16 MFMA) + per-pair geom/angle MLPs + diag + logit scale
__global__ __launch_bounds__(256, 3) void k_gp(const unsigned short* __restrict__ Ub,
        const unsigned short* __restrict__ Vb, const float* __restrict__ xy,
        const float* __restrict__ gW1, const float* __restrict__ gb1,
        const float* __restrict__ gW2, const float* __restrict__ gb2,
        const float* __restrict__ aW1, const float* __restrict__ ab1,
        const float* __restrict__ aW2, const float* __restrict__ ab2,
        const float* __restrict__ dv,
        const float* __restrict__ a_geom, const float* __restrict__ a_ang,
        const float* __restrict__ lsc,
        float* __restrict__ S){
    __shared__ float acc_lds[64][64];   // 16 KB
    int tid = threadIdx.x;
    int lane = tid & 63, l31 = lane & 31, hf = lane >> 5;
    int w = tid >> 6, wr = w >> 1, wc = w & 1;
    int b = blockIdx.z;
    int m0 = blockIdx.x*64, n0 = blockIdx.y*64;

    // ---------- phase 1: GEMM tile ----------
    {
        const unsigned short* ap = Ub + (size_t)(b*512 + n0 + wr*32 + l31)*UK + 8*hf;
        const unsigned short* bp = Vb + (size_t)(b*512 + m0 + wc*32 + l31)*UK + 8*hf;
        f32x16 acc = zero16();
        #pragma unroll 2
        for (int k0 = 0; k0 < UK; k0 += 16){
            short8 a  = *(const short8*)(ap + k0);
            short8 bb = *(const short8*)(bp + k0);
            acc = __builtin_amdgcn_mfma_f32_32x32x16_bf16(a, bb, acc, 0, 0, 0);
        }
        int colL = wc*32 + l31;
        int rbL  = wr*32 + 4*hf;
        #pragma unroll
        for (int r = 0; r < 16; r++)
            acc_lds[rbL + (r&3) + 8*(r>>2)][colL] = acc[r];
    }
    __syncthreads();

    // ---------- pair-MLP setup (weights/tables) ----------
    float sg = 1.5f*sigmoidf_(a_geom[0]);
    float sa = 1.5f*sigmoidf_(a_ang[0]);
    float ls = 0.5f + 2.5f*sigmoidf_(lsc[0]);

    short8 wg, wa;
    #pragma unroll
    for (int j = 0; j < 8; j++){
        int f = hf*8 + j;
        float vg = (f < 12) ? gW1[f*32 + l31] : 0.f;
        float va = (f >= 10 && l31 < 16) ? aW1[(f-10)*16 + l31] : 0.f;
        wg[j] = (short)f2bf(vg);
        wa[j] = (short)f2bf(va);
    }
    float nbg[16], g2g[16], nba[16], g2a[16];
    float bsum = 0.f;
    #pragma unroll
    for (int r = 0; r < 16; r++){
        int h = (r&3) + 8*(r>>2) + 4*hf;
        float bg  = gb1[h];
        float wg2 = sg*gW2[h];
        nbg[r] = -bg; g2g[r] = wg2; bsum += bg*wg2;
        if (h < 16){
            float ba  = ab1[h];
            float wa2 = sa*aW2[h];
            nba[r] = -ba; g2a[r] = wa2; bsum += ba*wa2;
        } else { nba[r] = 0.f; g2a[r] = 0.f; }
    }
    bsum += __shfl_xor(bsum, 32);
    float cb = sg*gb2[0] + sa*ab2[0] + bsum;

    const float GAMMA = 12.2499985f;    // 1/(2*spacing^2 + 1e-8)
    const float TWOGD = 4.9497469f;     // 2*GAMMA*spacing
    const float* xyb = xy + (size_t)b*1024;

    // ---------- phase 2: pair MLPs for 16 tile rows per wave ----------
    int m_w = m0 + lane;                // this lane's own pair column (dedup)
    float2 pmv = *(const float2*)(xyb + 2*m_w);
    float ym = pmv.x, xm = pmv.y;
    bool padm = (fabsf(ym) < 1e-9f) && (fabsf(xm) < 1e-9f);

    for (int i = 0; i < 16; i++){
        int nrow = (w << 4) + i;        // tile-local row, wave-uniform
        int nn = n0 + nrow;
        float yn = xyb[2*nn], xn = xyb[2*nn+1];
        bool padn = (fabsf(yn) < 1e-9f) && (fabsf(xn) < 1e-9f);
        float msk = (padn || padm) ? 0.f : 1.f;

        float dy = yn - ym, dx = xn - xm;
        float r2 = dy*dy + dx*dx;
        float re = sqrtf(r2 + 1e-8f);
        float c1, s1;
        if (r2 > 0.f){ float inv = rsqrtf(r2); c1 = dx*inv; s1 = dy*inv; }
        else { c1 = 1.f; s1 = 0.f; }    // atan2(0,0)=0
        float c2 = c1*c1 - s1*s1, s2 = 2.f*c1*s1;
        float c4 = c2*c2 - s2*s2, s4 = 2.f*c2*s2;
        float e0 = __expf(-GAMMA*(r2 + 1e-8f));
        float E  = __expf(TWOGD*re);
        float u  = e0;
        float p0 = u;
        u *= E; float p1 = 0.60653066f*u;
        u *= E; float p2 = 0.13533528f*u;
        u *= E; float p3 = 0.011108997f*u;
        u *= E; float p4 = 3.3546263e-4f*u;
        u *= E; float p5 = 3.7266532e-6f*u;
        u *= E; float p6 = 1.5229979e-8f*u;
        u *= E; float p7 = 2.2897348e-11f*u;
        unsigned pk0 = pk2(dy, dx), pk1 = pk2(p0, p1), pk2_ = pk2(p2, p3), pk3 = pk2(p4, p5);
        unsigned pk4 = pk2(p6, p7), pk5 = pk2(c1, s1), pk6 = pk2(c2, s2), pk7 = pk2(c4, s4);

        // exchange partner k-halves (selection evaluated in SOURCE lane)
        int s0 = __shfl_xor((int)(hf ? pk0 : pk4), 32);
        int s1i= __shfl_xor((int)(hf ? pk1 : pk5), 32);
        int s2i= __shfl_xor((int)(hf ? pk2_: pk6), 32);
        int s3i= __shfl_xor((int)(hf ? pk3 : pk7), 32);

        int fA0 = hf ? s0 : (int)pk0, fA1 = hf ? s1i : (int)pk1;
        int fA2 = hf ? s2i : (int)pk2_, fA3 = hf ? s3i : (int)pk3;
        int fB0 = hf ? (int)pk4 : s0,  fB1 = hf ? (int)pk5 : s1i;
        int fB2 = hf ? (int)pk6 : s2i, fB3 = hf ? (int)pk7 : s3i;
        int4v ivA = {fA0, fA1, fA2, fA3};
        int4v ivB = {fB0, fB1, fB2, fB3};
        short8 bfA = __builtin_bit_cast(short8, ivA);
        short8 bfB = __builtin_bit_cast(short8, ivB);

        f32x16 z = zero16();
        f32x16 dgA = __builtin_amdgcn_mfma_f32_32x32x16_bf16(wg, bfA, z, 0, 0, 0);
        f32x16 dgB = __builtin_amdgcn_mfma_f32_32x32x16_bf16(wg, bfB, z, 0, 0, 0);
        f32x16 daA = __builtin_amdgcn_mfma_f32_32x32x16_bf16(wa, bfA, z, 0, 0, 0);
        f32x16 daB = __builtin_amdgcn_mfma_f32_32x32x16_bf16(wa, bfB, z, 0, 0, 0);

        // tree reduce: 8 independent chains of 8
        float a0=0.f,a1=0.f,a2=0.f,a3=0.f,b0=0.f,b1=0.f,b2=0.f,b3=0.f;
        #pragma unroll
        for (int r = 0; r < 8; r++){
            a0 += fmaxf(dgA[r],   nbg[r])   * g2g[r];
            a1 += fmaxf(dgA[r+8], nbg[r+8]) * g2g[r+8];
            b0 += fmaxf(dgB[r],   nbg[r])   * g2g[r];
            b1 += fmaxf(dgB[r+8], nbg[r+8]) * g2g[r+8];
            a2 += fmaxf(daA[r],   nba[r])   * g2a[r];
            a3 += fmaxf(daA[r+8], nba[r+8]) * g2a[r+8];
            b2 += fmaxf(daB[r],   nba[r])   * g2a[r];
            b3 += fmaxf(daB[r+8], nba[r+8]) * g2a[r+8];
        }
        float accA = (a0 + a1) + (a2 + a3);
        float accB = (b0 + b1) + (b2 + b3);
        accA += __shfl_xor(accA, 32);
        accB += __shfl_xor(accB, 32);

        float res = (lane < 32) ? accA : accB;   // this lane's pair = m0+lane
        acc_lds[nrow][lane] += msk*(res + cb);
    }
    __syncthreads();

    // ---------- phase 3: diag + scale + single S store ----------
    {
        int m  = m0 + wc*32 + l31;
        int rbL = wr*32 + 4*hf;
        float* Sp = S + ((size_t)b*512)*512 + m;
        #pragma unroll
        for (int r = 0; r < 16; r++){
            int nloc = rbL + (r&3) + 8*(r>>2);
            int n = n0 + nloc;
            float v = acc_lds[nloc][wc*32 + l31];
            if (m == n) v += dv[b*512 + n];
            Sp[(size_t)n*512] = v * ls;
        }
    }
}

extern "C" void kernel_launch(void* const* d_in, const int* in_sizes, int n_in,
                              void* d_out, int out_size, void* d_ws, size_t ws_size,
                              hipStream_t stream){
    const float* feats = (const float*)d_in[0];
    const float* xy    = (const float*)d_in[1];
    const float* Wq    = (const float*)d_in[2];
    const float* Wk    = (const float*)d_in[3];
    const float* Wpi   = (const float*)d_in[4];
    const float* bpi   = (const float*)d_in[5];
    const float* Wpj   = (const float*)d_in[6];
    const float* bpj   = (const float*)d_in[7];
    const float* gW1   = (const float*)d_in[8];
    const float* gb1   = (const float*)d_in[9];
    const float* gW2   = (const float*)d_in[10];
    const float* gb2   = (const float*)d_in[11];
    const float* aW1   = (const float*)d_in[12];
    const float* ab1   = (const float*)d_in[13];
    const float* aW2   = (const float*)d_in[14];
    const float* ab2   = (const float*)d_in[15];
    const float* dW    = (const float*)d_in[16];
    const float* db    = (const float*)d_in[17];
    const float* a_pair= (const float*)d_in[18];
    const float* a_geom= (const float*)d_in[19];
    const float* a_ang = (const float*)d_in[20];
    const float* lsc   = (const float*)d_in[21];

    float* S = (float*)d_out;
    char* wsb = (char*)d_ws;
    unsigned short* xb = (unsigned short*)wsb;                    // 4096*256*2 = 2,097,152 B
    unsigned short* WT = (unsigned short*)(wsb + 2097152);        // 448*256*2  =   229,376 B
    unsigned short* Ub = (unsigned short*)(wsb + 2326528);        // 4096*224*2 = 1,835,008 B
    unsigned short* Vb = (unsigned short*)(wsb + 4161536);        // 1,835,008 B
    float* bcat = (float*)(wsb + 5996544);                        // 448*4
    float* dv   = (float*)(wsb + 5998336);                        // 4096*4
    // total ~6.0 MB of d_ws

    k_prep <<<4544, 256, 0, stream>>>(feats, Wq, Wk, Wpi, bpi, Wpj, bpj, dW, db, a_pair,
                                      xb, WT, bcat);
    k_uv   <<<dim3(7,64), 256, 0, stream>>>(xb, WT, bcat, Ub, Vb, dv);
    k_gp   <<<dim3(8,8,8), 256, 0, stream>>>(Ub, Vb, xy, gW1, gb1, gW2, gb2,
                                             aW1, ab1, aW2, ab2, dv,
                                             a_geom, a_ang, lsc, S);
}

// Round 19
// 50.746 us; speedup vs baseline: 2.6067x; 1.0262x over previous
//
#include <hip/hip_runtime.h>
#include <math.h>

// ScoreNet: B=8, NV=512, C=256, H=6, R=32, PAIR_H=16, RBF_K=8
// R19: k_gp occupancy fix — n-tile 64->32 (grid 1024 = 3 blocks/CU capped
//   = 12 waves/CU vs 8). Phase1: 4 waves split K (2x112) into two LDS
//   partials; phase2 identical R18 body (32 rows/block, 8 iters/wave);
//   phase3 sums partials + diag + ls, coalesced store.
// k_prep/k_uv unchanged.

#define UK 224

typedef __attribute__((ext_vector_type(8)))  short short8;
typedef __attribute__((ext_vector_type(16))) float f32x16;
typedef __attribute__((ext_vector_type(4)))  int   int4v;

__device__ __forceinline__ float sigmoidf_(float x){ return 1.0f/(1.0f + __expf(-x)); }
__device__ __forceinline__ unsigned f2bf(float x){
    unsigned u = __builtin_bit_cast(unsigned, x);
    return (u + 0x7fffu + ((u>>16)&1u)) >> 16;       // RNE f32->bf16
}
__device__ __forceinline__ unsigned pk2(float lo, float hi){
    unsigned r;
    asm("v_cvt_pk_bf16_f32 %0, %1, %2" : "=v"(r) : "v"(lo), "v"(hi));
    return r;
}
__device__ __forceinline__ f32x16 zero16(){
    f32x16 z;
    #pragma unroll
    for (int i = 0; i < 16; i++) z[i] = 0.f;
    return z;
}

// merged: blocks <4096 pool feats -> bf16 xb; blocks >=4096 pack WT (transposed, bf16) + bcat
__global__ __launch_bounds__(256) void k_prep(const float* __restrict__ feats,
        const float* __restrict__ Wq, const float* __restrict__ Wk,
        const float* __restrict__ Wpi, const float* __restrict__ bpi,
        const float* __restrict__ Wpj, const float* __restrict__ bpj,
        const float* __restrict__ dW, const float* __restrict__ db,
        const float* __restrict__ a_pair,
        unsigned short* __restrict__ xb, unsigned short* __restrict__ WT,
        float* __restrict__ bcat){
    int blk = blockIdx.x, tid = threadIdx.x;
    if (blk < 4096){
        int b = blk >> 9, n = blk & 511;
        size_t base = ((size_t)(b*1025 + 1 + 2*n))*256 + tid;
        float v = 0.5f*(feats[base] + feats[base+256]);
        xb[(size_t)blk*256 + tid] = (unsigned short)f2bf(v);
    } else {
        int col = blk - 4096;    // 0..447
        int c   = tid;           // k index 0..255
        const float invSqrtR = 0.17677669529663687f; // 1/sqrt(32)
        float sp = 1.5f*sigmoidf_(a_pair[0]);
        float v;
        if      (col < 192)  v = Wq[c*192 + col]*invSqrtR;
        else if (col < 208)  v = sp*Wpi[c*16 + (col-192)];
        else if (col < 400)  v = Wk[c*192 + (col-208)];
        else if (col < 416)  v = Wpj[c*16 + (col-400)];
        else if (col == 416) v = dW[c];
        else v = 0.f;
        WT[col*256 + c] = (unsigned short)f2bf(v);
        if (tid == 0){
            float bv = 0.f;
            if      (col >= 192 && col < 208) bv = sp*bpi[col-192];
            else if (col >= 400 && col < 416) bv = bpj[col-400];
            else if (col == 416)              bv = db[0];
            bcat[col] = bv;
        }
    }
}

// xb[4096][256] @ WT^T -> routed to Ub/Vb (bf16, [4096][224], zero-padded) + dv
__global__ __launch_bounds__(256) void k_uv(const unsigned short* __restrict__ xb,
        const unsigned short* __restrict__ WT, const float* __restrict__ bcat,
        unsigned short* __restrict__ Ub, unsigned short* __restrict__ Vb,
        float* __restrict__ dv){
    int tid = threadIdx.x;
    int lane = tid & 63, l31 = lane & 31, hf = lane >> 5;
    int w = tid >> 6, wr = w >> 1, wc = w & 1;
    int c0 = blockIdx.x*64, r0 = blockIdx.y*64;
    const unsigned short* ap = xb + (size_t)(r0 + wr*32 + l31)*256 + 8*hf;
    const unsigned short* bp = WT + (size_t)(c0 + wc*32 + l31)*256 + 8*hf;
    f32x16 acc = zero16();
    #pragma unroll 4
    for (int k0 = 0; k0 < 256; k0 += 16){
        short8 a  = *(const short8*)(ap + k0);
        short8 bb = *(const short8*)(bp + k0);
        acc = __builtin_amdgcn_mfma_f32_32x32x16_bf16(a, bb, acc, 0, 0, 0);
    }
    int col = c0 + wc*32 + l31;          // uniform per lane across all 16 accs
    int rb  = r0 + wr*32 + 4*hf;
    float bc = bcat[col];
    #pragma unroll
    for (int r = 0; r < 16; r++){
        int row = rb + (r&3) + 8*(r>>2);
        float v = acc[r] + bc;
        size_t ui = (size_t)row*UK;
        if (col < 208){
            if (col >= 192) v = fmaxf(v, 0.f);        // a_i relu
            Ub[ui + col] = (unsigned short)f2bf(v);
        } else if (col < 224){
            Vb[ui + col-208] = (unsigned short)f2bf(v);
            Ub[ui + col] = 0;                          // Ub K-pad
        } else if (col < 416){
            if (col >= 400) v = fmaxf(v, 0.f);        // b_j relu
            Vb[ui + col-208] = (unsigned short)f2bf(v);
        } else if (col == 416){
            dv[row] = v;
            Vb[ui + 208] = 0;                          // Vb K-pad
        } else if (col < 432){
            Vb[ui + col-208] = 0;                      // Vb K-pad (cols 417..431 are zero-cols)
        }
        // col >= 432: dead padding, skip
    }
}

// FUSED: S_lin (bf16 MFMA, K-split) + pair MLPs + diag + logit scale
// tile: 32 n-rows x 64 m-cols; grid dim3(8,16,8)
__global__ __launch_bounds__(256, 3) void k_gp(const unsigned short* __restrict__ Ub,
        const unsigned short* __restrict__ Vb, const float* __restrict__ xy,
        const float* __restrict__ gW1, const float* __restrict__ gb1,
        const float* __restrict__ gW2, const float* __restrict__ gb2,
        const float* __restrict__ aW1, const float* __restrict__ ab1,
        const float* __restrict__ aW2, const float* __restrict__ ab2,
        const float* __restrict__ dv,
        const float* __restrict__ a_geom, const float* __restrict__ a_ang,
        const float* __restrict__ lsc,
        float* __restrict__ S){
    __shared__ float acc_lds[2][32][64];   // two K-partials, 16 KB
    int tid = threadIdx.x;
    int lane = tid & 63, l31 = lane & 31, hf = lane >> 5;
    int w = tid >> 6, wr = w >> 1, wc = w & 1;   // wr = K-half, wc = m-half
    int b = blockIdx.z;
    int m0 = blockIdx.x*64, n0 = blockIdx.y*32;

    // ---------- phase 1: GEMM tile (K split across wave pairs) ----------
    {
        const unsigned short* ap = Ub + (size_t)(b*512 + n0 + l31)*UK + wr*112 + 8*hf;
        const unsigned short* bp = Vb + (size_t)(b*512 + m0 + wc*32 + l31)*UK + wr*112 + 8*hf;
        f32x16 acc = zero16();
        #pragma unroll
        for (int t = 0; t < 7; t++){
            short8 a  = *(const short8*)(ap + t*16);
            short8 bb = *(const short8*)(bp + t*16);
            acc = __builtin_amdgcn_mfma_f32_32x32x16_bf16(a, bb, acc, 0, 0, 0);
        }
        int colL = wc*32 + l31;
        #pragma unroll
        for (int r = 0; r < 16; r++)
            acc_lds[wr][(r&3) + 8*(r>>2) + 4*hf][colL] = acc[r];
    }
    __syncthreads();

    // ---------- pair-MLP setup (weights/tables) ----------
    float sg = 1.5f*sigmoidf_(a_geom[0]);
    float sa = 1.5f*sigmoidf_(a_ang[0]);
    float ls = 0.5f + 2.5f*sigmoidf_(lsc[0]);

    short8 wg, wa;
    #pragma unroll
    for (int j = 0; j < 8; j++){
        int f = hf*8 + j;
        float vg = (f < 12) ? gW1[f*32 + l31] : 0.f;
        float va = (f >= 10 && l31 < 16) ? aW1[(f-10)*16 + l31] : 0.f;
        wg[j] = (short)f2bf(vg);
        wa[j] = (short)f2bf(va);
    }
    float nbg[16], g2g[16], nba[16], g2a[16];
    float bsum = 0.f;
    #pragma unroll
    for (int r = 0; r < 16; r++){
        int h = (r&3) + 8*(r>>2) + 4*hf;
        float bg  = gb1[h];
        float wg2 = sg*gW2[h];
        nbg[r] = -bg; g2g[r] = wg2; bsum += bg*wg2;
        if (h < 16){
            float ba  = ab1[h];
            float wa2 = sa*aW2[h];
            nba[r] = -ba; g2a[r] = wa2; bsum += ba*wa2;
        } else { nba[r] = 0.f; g2a[r] = 0.f; }
    }
    bsum += __shfl_xor(bsum, 32);
    float cb = sg*gb2[0] + sa*ab2[0] + bsum;

    const float GAMMA = 12.2499985f;    // 1/(2*spacing^2 + 1e-8)
    const float TWOGD = 4.9497469f;     // 2*GAMMA*spacing
    const float* xyb = xy + (size_t)b*1024;

    // ---------- phase 2: pair MLPs for 8 tile rows per wave ----------
    int m_w = m0 + lane;                // this lane's own pair column (dedup)
    float2 pmv = *(const float2*)(xyb + 2*m_w);
    float ym = pmv.x, xm = pmv.y;
    bool padm = (fabsf(ym) < 1e-9f) && (fabsf(xm) < 1e-9f);

    for (int i = 0; i < 8; i++){
        int nrow = (w << 3) + i;        // tile-local row, wave-uniform
        int nn = n0 + nrow;
        float yn = xyb[2*nn], xn = xyb[2*nn+1];
        bool padn = (fabsf(yn) < 1e-9f) && (fabsf(xn) < 1e-9f);
        float msk = (padn || padm) ? 0.f : 1.f;

        float dy = yn - ym, dx = xn - xm;
        float r2 = dy*dy + dx*dx;
        float re = sqrtf(r2 + 1e-8f);
        float c1, s1;
        if (r2 > 0.f){ float inv = rsqrtf(r2); c1 = dx*inv; s1 = dy*inv; }
        else { c1 = 1.f; s1 = 0.f; }    // atan2(0,0)=0
        float c2 = c1*c1 - s1*s1, s2 = 2.f*c1*s1;
        float c4 = c2*c2 - s2*s2, s4 = 2.f*c2*s2;
        float e0 = __expf(-GAMMA*(r2 + 1e-8f));
        float E  = __expf(TWOGD*re);
        float u  = e0;
        float p0 = u;
        u *= E; float p1 = 0.60653066f*u;
        u *= E; float p2 = 0.13533528f*u;
        u *= E; float p3 = 0.011108997f*u;
        u *= E; float p4 = 3.3546263e-4f*u;
        u *= E; float p5 = 3.7266532e-6f*u;
        u *= E; float p6 = 1.5229979e-8f*u;
        u *= E; float p7 = 2.2897348e-11f*u;
        unsigned pk0 = pk2(dy, dx), pk1 = pk2(p0, p1), pk2_ = pk2(p2, p3), pk3 = pk2(p4, p5);
        unsigned pk4 = pk2(p6, p7), pk5 = pk2(c1, s1), pk6 = pk2(c2, s2), pk7 = pk2(c4, s4);

        // exchange partner k-halves (selection evaluated in SOURCE lane)
        int s0 = __shfl_xor((int)(hf ? pk0 : pk4), 32);
        int s1i= __shfl_xor((int)(hf ? pk1 : pk5), 32);
        int s2i= __shfl_xor((int)(hf ? pk2_: pk6), 32);
        int s3i= __shfl_xor((int)(hf ? pk3 : pk7), 32);

        int fA0 = hf ? s0 : (int)pk0, fA1 = hf ? s1i : (int)pk1;
        int fA2 = hf ? s2i : (int)pk2_, fA3 = hf ? s3i : (int)pk3;
        int fB0 = hf ? (int)pk4 : s0,  fB1 = hf ? (int)pk5 : s1i;
        int fB2 = hf ? (int)pk6 : s2i, fB3 = hf ? (int)pk7 : s3i;
        int4v ivA = {fA0, fA1, fA2, fA3};
        int4v ivB = {fB0, fB1, fB2, fB3};
        short8 bfA = __builtin_bit_cast(short8, ivA);
        short8 bfB = __builtin_bit_cast(short8, ivB);

        f32x16 z = zero16();
        f32x16 dgA = __builtin_amdgcn_mfma_f32_32x32x16_bf16(wg, bfA, z, 0, 0, 0);
        f32x16 dgB = __builtin_amdgcn_mfma_f32_32x32x16_bf16(wg, bfB, z, 0, 0, 0);
        f32x16 daA = __builtin_amdgcn_mfma_f32_32x32x16_bf16(wa, bfA, z, 0, 0, 0);
        f32x16 daB = __builtin_amdgcn_mfma_f32_32x32x16_bf16(wa, bfB, z, 0, 0, 0);

        // tree reduce: 8 independent chains of 8
        float a0=0.f,a1=0.f,a2=0.f,a3=0.f,b0=0.f,b1=0.f,b2=0.f,b3=0.f;
        #pragma unroll
        for (int r = 0; r < 8; r++){
            a0 += fmaxf(dgA[r],   nbg[r])   * g2g[r];
            a1 += fmaxf(dgA[r+8], nbg[r+8]) * g2g[r+8];
            b0 += fmaxf(dgB[r],   nbg[r])   * g2g[r];
            b1 += fmaxf(dgB[r+8], nbg[r+8]) * g2g[r+8];
            a2 += fmaxf(daA[r],   nba[r])   * g2a[r];
            a3 += fmaxf(daA[r+8], nba[r+8]) * g2a[r+8];
            b2 += fmaxf(daB[r],   nba[r])   * g2a[r];
            b3 += fmaxf(daB[r+8], nba[r+8]) * g2a[r+8];
        }
        float accA = (a0 + a1) + (a2 + a3);
        float accB = (b0 + b1) + (b2 + b3);
        accA += __shfl_xor(accA, 32);
        accB += __shfl_xor(accB, 32);

        float res = (lane < 32) ? accA : accB;   // this lane's pair = m0+lane
        acc_lds[0][nrow][lane] += msk*(res + cb);
    }
    __syncthreads();

    // ---------- phase 3: sum K-partials + diag + scale + coalesced store ----------
    {
        float dvb = 0.f;  // loaded per row below
        #pragma unroll
        for (int j = 0; j < 8; j++){
            int flat = tid + j*256;          // 0..2047
            int row = flat >> 6, col = flat & 63;
            float v = acc_lds[0][row][col] + acc_lds[1][row][col];
            int n = n0 + row, m = m0 + col;
            if (m == n) v += dv[b*512 + n];
            S[((size_t)b*512 + n)*512 + m] = v * ls;
        }
        (void)dvb;
    }
}

extern "C" void kernel_launch(void* const* d_in, const int* in_sizes, int n_in,
                              void* d_out, int out_size, void* d_ws, size_t ws_size,
                              hipStream_t stream){
    const float* feats = (const float*)d_in[0];
    const float* xy    = (const float*)d_in[1];
    const float* Wq    = (const float*)d_in[2];
    const float* Wk    = (const float*)d_in[3];
    const float* Wpi   = (const float*)d_in[4];
    const float* bpi   = (const float*)d_in[5];
    const float* Wpj   = (const float*)d_in[6];
    const float* bpj   = (const float*)d_in[7];
    const float* gW1   = (const float*)d_in[8];
    const float* gb1   = (const float*)d_in[9];
    const float* gW2   = (const float*)d_in[10];
    const float* gb2   = (const float*)d_in[11];
    const float* aW1   = (const float*)d_in[12];
    const float* ab1   = (const float*)d_in[13];
    const float* aW2   = (const float*)d_in[14];
    const float* ab2   = (const float*)d_in[15];
    const float* dW    = (const float*)d_in[16];
    const float* db    = (const float*)d_in[17];
    const float* a_pair= (const float*)d_in[18];
    const float* a_geom= (const float*)d_in[19];
    const float* a_ang = (const float*)d_in[20];
    const float* lsc   = (const float*)d_in[21];

    float* S = (float*)d_out;
    char* wsb = (char*)d_ws;
    unsigned short* xb = (unsigned short*)wsb;                    // 4096*256*2 = 2,097,152 B
    unsigned short* WT = (unsigned short*)(wsb + 2097152);        // 448*256*2  =   229,376 B
    unsigned short* Ub = (unsigned short*)(wsb + 2326528);        // 4096*224*2 = 1,835,008 B
    unsigned short* Vb = (unsigned short*)(wsb + 4161536);        // 1,835,008 B
    float* bcat = (float*)(wsb + 5996544);                        // 448*4
    float* dv   = (float*)(wsb + 5998336);                        // 4096*4
    // total ~6.0 MB of d_ws

    k_prep <<<4544, 256, 0, stream>>>(feats, Wq, Wk, Wpi, bpi, Wpj, bpj, dW, db, a_pair,
                                      xb, WT, bcat);
    k_uv   <<<dim3(7,64), 256, 0, stream>>>(xb, WT, bcat, Ub, Vb, dv);
    k_gp   <<<dim3(8,16,8), 256, 0, stream>>>(Ub, Vb, xy, gW1, gb1, gW2, gb2,
                                              aW1, ab1, aW2, ab2, dv,
                                              a_geom, a_ang, lsc, S);
}

// Round 20
// 48.883 us; speedup vs baseline: 2.7060x; 1.0381x over previous
//
#include <hip/hip_runtime.h>
#include <math.h>

// ScoreNet: B=8, NV=512, C=256, H=6, R=32, PAIR_H=16, RBF_K=8
// R20: cut provably-zero reduce work in k_gp phase 2 — angle C/D rows map to
//   h=(r&3)+8*(r>>2)+4*hf which is >=16 for r=8..15 on BOTH wave halves, so
//   the a3/b3 chains were fmaxf(x,0)*0. Reduce 128->96 ops/iter/lane; angle
//   tables 16->8 entries. Bit-identical output. Everything else = R19.

#define UK 224

typedef __attribute__((ext_vector_type(8)))  short short8;
typedef __attribute__((ext_vector_type(16))) float f32x16;
typedef __attribute__((ext_vector_type(4)))  int   int4v;

__device__ __forceinline__ float sigmoidf_(float x){ return 1.0f/(1.0f + __expf(-x)); }
__device__ __forceinline__ unsigned f2bf(float x){
    unsigned u = __builtin_bit_cast(unsigned, x);
    return (u + 0x7fffu + ((u>>16)&1u)) >> 16;       // RNE f32->bf16
}
__device__ __forceinline__ unsigned pk2(float lo, float hi){
    unsigned r;
    asm("v_cvt_pk_bf16_f32 %0, %1, %2" : "=v"(r) : "v"(lo), "v"(hi));
    return r;
}
__device__ __forceinline__ f32x16 zero16(){
    f32x16 z;
    #pragma unroll
    for (int i = 0; i < 16; i++) z[i] = 0.f;
    return z;
}

// merged: blocks <4096 pool feats -> bf16 xb; blocks >=4096 pack WT (transposed, bf16) + bcat
__global__ __launch_bounds__(256) void k_prep(const float* __restrict__ feats,
        const float* __restrict__ Wq, const float* __restrict__ Wk,
        const float* __restrict__ Wpi, const float* __restrict__ bpi,
        const float* __restrict__ Wpj, const float* __restrict__ bpj,
        const float* __restrict__ dW, const float* __restrict__ db,
        const float* __restrict__ a_pair,
        unsigned short* __restrict__ xb, unsigned short* __restrict__ WT,
        float* __restrict__ bcat){
    int blk = blockIdx.x, tid = threadIdx.x;
    if (blk < 4096){
        int b = blk >> 9, n = blk & 511;
        size_t base = ((size_t)(b*1025 + 1 + 2*n))*256 + tid;
        float v = 0.5f*(feats[base] + feats[base+256]);
        xb[(size_t)blk*256 + tid] = (unsigned short)f2bf(v);
    } else {
        int col = blk - 4096;    // 0..447
        int c   = tid;           // k index 0..255
        const float invSqrtR = 0.17677669529663687f; // 1/sqrt(32)
        float sp = 1.5f*sigmoidf_(a_pair[0]);
        float v;
        if      (col < 192)  v = Wq[c*192 + col]*invSqrtR;
        else if (col < 208)  v = sp*Wpi[c*16 + (col-192)];
        else if (col < 400)  v = Wk[c*192 + (col-208)];
        else if (col < 416)  v = Wpj[c*16 + (col-400)];
        else if (col == 416) v = dW[c];
        else v = 0.f;
        WT[col*256 + c] = (unsigned short)f2bf(v);
        if (tid == 0){
            float bv = 0.f;
            if      (col >= 192 && col < 208) bv = sp*bpi[col-192];
            else if (col >= 400 && col < 416) bv = bpj[col-400];
            else if (col == 416)              bv = db[0];
            bcat[col] = bv;
        }
    }
}

// xb[4096][256] @ WT^T -> routed to Ub/Vb (bf16, [4096][224], zero-padded) + dv
__global__ __launch_bounds__(256) void k_uv(const unsigned short* __restrict__ xb,
        const unsigned short* __restrict__ WT, const float* __restrict__ bcat,
        unsigned short* __restrict__ Ub, unsigned short* __restrict__ Vb,
        float* __restrict__ dv){
    int tid = threadIdx.x;
    int lane = tid & 63, l31 = lane & 31, hf = lane >> 5;
    int w = tid >> 6, wr = w >> 1, wc = w & 1;
    int c0 = blockIdx.x*64, r0 = blockIdx.y*64;
    const unsigned short* ap = xb + (size_t)(r0 + wr*32 + l31)*256 + 8*hf;
    const unsigned short* bp = WT + (size_t)(c0 + wc*32 + l31)*256 + 8*hf;
    f32x16 acc = zero16();
    #pragma unroll 4
    for (int k0 = 0; k0 < 256; k0 += 16){
        short8 a  = *(const short8*)(ap + k0);
        short8 bb = *(const short8*)(bp + k0);
        acc = __builtin_amdgcn_mfma_f32_32x32x16_bf16(a, bb, acc, 0, 0, 0);
    }
    int col = c0 + wc*32 + l31;          // uniform per lane across all 16 accs
    int rb  = r0 + wr*32 + 4*hf;
    float bc = bcat[col];
    #pragma unroll
    for (int r = 0; r < 16; r++){
        int row = rb + (r&3) + 8*(r>>2);
        float v = acc[r] + bc;
        size_t ui = (size_t)row*UK;
        if (col < 208){
            if (col >= 192) v = fmaxf(v, 0.f);        // a_i relu
            Ub[ui + col] = (unsigned short)f2bf(v);
        } else if (col < 224){
            Vb[ui + col-208] = (unsigned short)f2bf(v);
            Ub[ui + col] = 0;                          // Ub K-pad
        } else if (col < 416){
            if (col >= 400) v = fmaxf(v, 0.f);        // b_j relu
            Vb[ui + col-208] = (unsigned short)f2bf(v);
        } else if (col == 416){
            dv[row] = v;
            Vb[ui + 208] = 0;                          // Vb K-pad
        } else if (col < 432){
            Vb[ui + col-208] = 0;                      // Vb K-pad (cols 417..431 are zero-cols)
        }
        // col >= 432: dead padding, skip
    }
}

// FUSED: S_lin (bf16 MFMA, K-split) + pair MLPs + diag + logit scale
// tile: 32 n-rows x 64 m-cols; grid dim3(8,16,8)
__global__ __launch_bounds__(256, 3) void k_gp(const unsigned short* __restrict__ Ub,
        const unsigned short* __restrict__ Vb, const float* __restrict__ xy,
        const float* __restrict__ gW1, const float* __restrict__ gb1,
        const float* __restrict__ gW2, const float* __restrict__ gb2,
        const float* __restrict__ aW1, const float* __restrict__ ab1,
        const float* __restrict__ aW2, const float* __restrict__ ab2,
        const float* __restrict__ dv,
        const float* __restrict__ a_geom, const float* __restrict__ a_ang,
        const float* __restrict__ lsc,
        float* __restrict__ S){
    __shared__ float acc_lds[2][32][64];   // two K-partials, 16 KB
    int tid = threadIdx.x;
    int lane = tid & 63, l31 = lane & 31, hf = lane >> 5;
    int w = tid >> 6, wr = w >> 1, wc = w & 1;   // wr = K-half, wc = m-half
    int b = blockIdx.z;
    int m0 = blockIdx.x*64, n0 = blockIdx.y*32;

    // ---------- phase 1: GEMM tile (K split across wave pairs) ----------
    {
        const unsigned short* ap = Ub + (size_t)(b*512 + n0 + l31)*UK + wr*112 + 8*hf;
        const unsigned short* bp = Vb + (size_t)(b*512 + m0 + wc*32 + l31)*UK + wr*112 + 8*hf;
        f32x16 acc = zero16();
        #pragma unroll
        for (int t = 0; t < 7; t++){
            short8 a  = *(const short8*)(ap + t*16);
            short8 bb = *(const short8*)(bp + t*16);
            acc = __builtin_amdgcn_mfma_f32_32x32x16_bf16(a, bb, acc, 0, 0, 0);
        }
        int colL = wc*32 + l31;
        #pragma unroll
        for (int r = 0; r < 16; r++)
            acc_lds[wr][(r&3) + 8*(r>>2) + 4*hf][colL] = acc[r];
    }
    __syncthreads();

    // ---------- pair-MLP setup (weights/tables) ----------
    float sg = 1.5f*sigmoidf_(a_geom[0]);
    float sa = 1.5f*sigmoidf_(a_ang[0]);
    float ls = 0.5f + 2.5f*sigmoidf_(lsc[0]);

    short8 wg, wa;
    #pragma unroll
    for (int j = 0; j < 8; j++){
        int f = hf*8 + j;
        float vg = (f < 12) ? gW1[f*32 + l31] : 0.f;
        float va = (f >= 10 && l31 < 16) ? aW1[(f-10)*16 + l31] : 0.f;
        wg[j] = (short)f2bf(vg);
        wa[j] = (short)f2bf(va);
    }
    // geom tables: all 16 regs; angle tables: only r=0..7 have h<16
    float nbg[16], g2g[16], nba[8], g2a[8];
    float bsum = 0.f;
    #pragma unroll
    for (int r = 0; r < 16; r++){
        int h = (r&3) + 8*(r>>2) + 4*hf;
        float bg  = gb1[h];
        float wg2 = sg*gW2[h];
        nbg[r] = -bg; g2g[r] = wg2; bsum += bg*wg2;
        if (r < 8){   // h<16 exactly when r<8 (both halves)
            float ba  = ab1[h];
            float wa2 = sa*aW2[h];
            nba[r] = -ba; g2a[r] = wa2; bsum += ba*wa2;
        }
    }
    bsum += __shfl_xor(bsum, 32);
    float cb = sg*gb2[0] + sa*ab2[0] + bsum;

    const float GAMMA = 12.2499985f;    // 1/(2*spacing^2 + 1e-8)
    const float TWOGD = 4.9497469f;     // 2*GAMMA*spacing
    const float* xyb = xy + (size_t)b*1024;

    // ---------- phase 2: pair MLPs for 8 tile rows per wave ----------
    int m_w = m0 + lane;                // this lane's own pair column (dedup)
    float2 pmv = *(const float2*)(xyb + 2*m_w);
    float ym = pmv.x, xm = pmv.y;
    bool padm = (fabsf(ym) < 1e-9f) && (fabsf(xm) < 1e-9f);

    for (int i = 0; i < 8; i++){
        int nrow = (w << 3) + i;        // tile-local row, wave-uniform
        int nn = n0 + nrow;
        float yn = xyb[2*nn], xn = xyb[2*nn+1];
        bool padn = (fabsf(yn) < 1e-9f) && (fabsf(xn) < 1e-9f);
        float msk = (padn || padm) ? 0.f : 1.f;

        float dy = yn - ym, dx = xn - xm;
        float r2 = dy*dy + dx*dx;
        float re = sqrtf(r2 + 1e-8f);
        float c1, s1;
        if (r2 > 0.f){ float inv = rsqrtf(r2); c1 = dx*inv; s1 = dy*inv; }
        else { c1 = 1.f; s1 = 0.f; }    // atan2(0,0)=0
        float c2 = c1*c1 - s1*s1, s2 = 2.f*c1*s1;
        float c4 = c2*c2 - s2*s2, s4 = 2.f*c2*s2;
        float e0 = __expf(-GAMMA*(r2 + 1e-8f));
        float E  = __expf(TWOGD*re);
        float u  = e0;
        float p0 = u;
        u *= E; float p1 = 0.60653066f*u;
        u *= E; float p2 = 0.13533528f*u;
        u *= E; float p3 = 0.011108997f*u;
        u *= E; float p4 = 3.3546263e-4f*u;
        u *= E; float p5 = 3.7266532e-6f*u;
        u *= E; float p6 = 1.5229979e-8f*u;
        u *= E; float p7 = 2.2897348e-11f*u;
        unsigned pk0 = pk2(dy, dx), pk1 = pk2(p0, p1), pk2_ = pk2(p2, p3), pk3 = pk2(p4, p5);
        unsigned pk4 = pk2(p6, p7), pk5 = pk2(c1, s1), pk6 = pk2(c2, s2), pk7 = pk2(c4, s4);

        // exchange partner k-halves (selection evaluated in SOURCE lane)
        int s0 = __shfl_xor((int)(hf ? pk0 : pk4), 32);
        int s1i= __shfl_xor((int)(hf ? pk1 : pk5), 32);
        int s2i= __shfl_xor((int)(hf ? pk2_: pk6), 32);
        int s3i= __shfl_xor((int)(hf ? pk3 : pk7), 32);

        int fA0 = hf ? s0 : (int)pk0, fA1 = hf ? s1i : (int)pk1;
        int fA2 = hf ? s2i : (int)pk2_, fA3 = hf ? s3i : (int)pk3;
        int fB0 = hf ? (int)pk4 : s0,  fB1 = hf ? (int)pk5 : s1i;
        int fB2 = hf ? (int)pk6 : s2i, fB3 = hf ? (int)pk7 : s3i;
        int4v ivA = {fA0, fA1, fA2, fA3};
        int4v ivB = {fB0, fB1, fB2, fB3};
        short8 bfA = __builtin_bit_cast(short8, ivA);
        short8 bfB = __builtin_bit_cast(short8, ivB);

        f32x16 z = zero16();
        f32x16 dgA = __builtin_amdgcn_mfma_f32_32x32x16_bf16(wg, bfA, z, 0, 0, 0);
        f32x16 dgB = __builtin_amdgcn_mfma_f32_32x32x16_bf16(wg, bfB, z, 0, 0, 0);
        f32x16 daA = __builtin_amdgcn_mfma_f32_32x32x16_bf16(wa, bfA, z, 0, 0, 0);
        f32x16 daB = __builtin_amdgcn_mfma_f32_32x32x16_bf16(wa, bfB, z, 0, 0, 0);

        // tree reduce: geom 16 regs (2 chains each), angle only r=0..7 (h<16)
        float a0=0.f,a1=0.f,a2=0.f,b0=0.f,b1=0.f,b2=0.f;
        #pragma unroll
        for (int r = 0; r < 8; r++){
            a0 += fmaxf(dgA[r],   nbg[r])   * g2g[r];
            a1 += fmaxf(dgA[r+8], nbg[r+8]) * g2g[r+8];
            b0 += fmaxf(dgB[r],   nbg[r])   * g2g[r];
            b1 += fmaxf(dgB[r+8], nbg[r+8]) * g2g[r+8];
            a2 += fmaxf(daA[r],   nba[r])   * g2a[r];
            b2 += fmaxf(daB[r],   nba[r])   * g2a[r];
        }
        float accA = (a0 + a1) + a2;
        float accB = (b0 + b1) + b2;
        accA += __shfl_xor(accA, 32);
        accB += __shfl_xor(accB, 32);

        float res = (lane < 32) ? accA : accB;   // this lane's pair = m0+lane
        acc_lds[0][nrow][lane] += msk*(res + cb);
    }
    __syncthreads();

    // ---------- phase 3: sum K-partials + diag + scale + coalesced store ----------
    {
        #pragma unroll
        for (int j = 0; j < 8; j++){
            int flat = tid + j*256;          // 0..2047
            int row = flat >> 6, col = flat & 63;
            float v = acc_lds[0][row][col] + acc_lds[1][row][col];
            int n = n0 + row, m = m0 + col;
            if (m == n) v += dv[b*512 + n];
            S[((size_t)b*512 + n)*512 + m] = v * ls;
        }
    }
}

extern "C" void kernel_launch(void* const* d_in, const int* in_sizes, int n_in,
                              void* d_out, int out_size, void* d_ws, size_t ws_size,
                              hipStream_t stream){
    const float* feats = (const float*)d_in[0];
    const float* xy    = (const float*)d_in[1];
    const float* Wq    = (const float*)d_in[2];
    const float* Wk    = (const float*)d_in[3];
    const float* Wpi   = (const float*)d_in[4];
    const float* bpi   = (const float*)d_in[5];
    const float* Wpj   = (const float*)d_in[6];
    const float* bpj   = (const float*)d_in[7];
    const float* gW1   = (const float*)d_in[8];
    const float* gb1   = (const float*)d_in[9];
    const float* gW2   = (const float*)d_in[10];
    const float* gb2   = (const float*)d_in[11];
    const float* aW1   = (const float*)d_in[12];
    const float* ab1   = (const float*)d_in[13];
    const float* aW2   = (const float*)d_in[14];
    const float* ab2   = (const float*)d_in[15];
    const float* dW    = (const float*)d_in[16];
    const float* db    = (const float*)d_in[17];
    const float* a_pair= (const float*)d_in[18];
    const float* a_geom= (const float*)d_in[19];
    const float* a_ang = (const float*)d_in[20];
    const float* lsc   = (const float*)d_in[21];

    float* S = (float*)d_out;
    char* wsb = (char*)d_ws;
    unsigned short* xb = (unsigned short*)wsb;                    // 4096*256*2 = 2,097,152 B
    unsigned short* WT = (unsigned short*)(wsb + 2097152);        // 448*256*2  =   229,376 B
    unsigned short* Ub = (unsigned short*)(wsb + 2326528);        // 4096*224*2 = 1,835,008 B
    unsigned short* Vb = (unsigned short*)(wsb + 4161536);        // 1,835,008 B
    float* bcat = (float*)(wsb + 5996544);                        // 448*4
    float* dv   = (float*)(wsb + 5998336);                        // 4096*4
    // total ~6.0 MB of d_ws

    k_prep <<<4544, 256, 0, stream>>>(feats, Wq, Wk, Wpi, bpi, Wpj, bpj, dW, db, a_pair,
                                      xb, WT, bcat);
    k_uv   <<<dim3(7,64), 256, 0, stream>>>(xb, WT, bcat, Ub, Vb, dv);
    k_gp   <<<dim3(8,16,8), 256, 0, stream>>>(Ub, Vb, xy, gW1, gb1, gW2, gb2,
                                              aW1, ab1, aW2, ab2, dv,
                                              a_geom, a_ang, lsc, S);
}